// Round 7
// baseline (408.628 us; speedup 1.0000x reference)
//
#include <hip/hip_runtime.h>
#include <hip/hip_bf16.h>

#define BB 256
#define PP 48
#define NN 64
#define EPSBN 1e-5f

typedef __attribute__((ext_vector_type(8))) short bf16x8;
typedef __attribute__((ext_vector_type(4))) float f32x4;

// ---- LDS (ushort offsets), total 40960 u = 81920 B -> 2 blocks/CU ----
#define S1SO 0       // 16384: S1S [64][256]            | N: act1N [64][256]; then red/h1/h2 floats
#define S1RO 16384   // 16384: S1R [64][256]; cols 0..63 -> ebar; N: act0 (ebar+xn)
#define A2WO 32768   //  8192: prologue xnT [64][64] | phase E: 4 waves x 2048 act2 | N: act2N [64][128]
#define LDSE 40960

// ---- workspace tiled-weight offsets (ushorts, after 128 floats) ----
#define T1R 0        // fr1 recv half  M=256 K=64  (16 mt x 2 ks)
#define T1S 16384    // fr1 send half
#define T2O 32768    // fr2            M=128 K=256 (8 x 8)
#define T3O 65536    // fr3            M=64  K=128 (4 x 4)
#define TO1 73728    // fo1 permuted   M=256 K=128 (16 x 4)
#define TO2 106496   // fo2            M=128 K=256 (8 x 8)
#define TO3 139264   // fo3            M=64  K=128 (4 x 4)
#define WSU_TOTAL 147456

union U8 { bf16x8 v; unsigned u[4]; };

__device__ __forceinline__ unsigned pku(float a, float b) {
    union { __hip_bfloat162 h; unsigned u; } cv;
    cv.h = __float22bfloat162_rn(make_float2(a, b));
    return cv.u;
}
__device__ __forceinline__ ushort f2b(float f) {
    union { float f; unsigned u; } a; a.f = f;
    unsigned u = a.u + 0x7FFFu + ((a.u >> 16) & 1u);
    return (ushort)(u >> 16);
}
__device__ __forceinline__ float loF(unsigned u) { union { unsigned x; float f; } c; c.x = u << 16; return c.f; }
__device__ __forceinline__ float hiF(unsigned u) { union { unsigned x; float f; } c; c.x = u & 0xffff0000u; return c.f; }

__device__ __forceinline__ int sidx(int row, int k, int kpad) {
    return row * kpad + ((((k >> 3) ^ (row & 7)) << 3) | (k & 7));
}
__device__ __forceinline__ bf16x8 ldfrag(const ushort* buf, int row, int k, int kpad) {
    return *(const bf16x8*)(buf + row * kpad + (((k >> 3) ^ (row & 7)) << 3));
}
// coalesced tiled-fragment load from global workspace: frag f, lane l -> 16 B
__device__ __forceinline__ bf16x8 gfrag(const ushort* base, int f, int l) {
    return *(const bf16x8*)(base + ((f << 6) + l) * 8);
}
__device__ __forceinline__ f32x4 MFMA(bf16x8 a, bf16x8 b, f32x4 c) {
    return __builtin_amdgcn_mfma_f32_16x16x32_bf16(a, b, c, 0, 0, 0);
}
__device__ __forceinline__ void stAct(ushort* buf, int row, int c0, int kpad, f32x4 a, float4 bi) {
    uint2 o;
    o.x = pku(fmaxf(a[0] + bi.x, 0.f), fmaxf(a[1] + bi.y, 0.f));
    o.y = pku(fmaxf(a[2] + bi.z, 0.f), fmaxf(a[3] + bi.w, 0.f));
    *(uint2*)(buf + row * kpad + ((((c0 >> 3) ^ (row & 7)) << 3) | (c0 & 7))) = o;
}
__device__ __forceinline__ void stRaw(ushort* buf, int row, int c0, int kpad, f32x4 a, float4 bi) {
    uint2 o;
    o.x = pku(a[0] + bi.x, a[1] + bi.y);
    o.y = pku(a[2] + bi.z, a[3] + bi.w);
    *(uint2*)(buf + row * kpad + ((((c0 >> 3) ^ (row & 7)) << 3) | (c0 & 7))) = o;
}

// ---------------- batchnorm stats ----------------
__global__ __launch_bounds__(256) void bn_stats_kernel(
    const float* __restrict__ x, const float* __restrict__ gamma,
    const float* __restrict__ beta, float* __restrict__ scale, float* __restrict__ bias)
{
    __shared__ float s_sum[256], s_sq[256];
    int p = blockIdx.x, t = threadIdx.x;
    float sum = 0.f, sq = 0.f;
    for (int i = t; i < BB * NN; i += 256) {
        int b = i >> 6, n = i & 63;
        float v = x[b * PP * NN + p * NN + n];
        sum += v; sq += v * v;
    }
    s_sum[t] = sum; s_sq[t] = sq;
    __syncthreads();
    for (int off = 128; off > 0; off >>= 1) {
        if (t < off) { s_sum[t] += s_sum[t + off]; s_sq[t] += s_sq[t + off]; }
        __syncthreads();
    }
    if (t == 0) {
        float inv = 1.f / (float)(BB * NN);
        float mean = s_sum[0] * inv;
        float var  = s_sq[0] * inv - mean * mean;
        float sc   = gamma[p] * rsqrtf(var + EPSBN);
        scale[p] = sc;
        bias[p]  = beta[p] - mean * sc;
    }
}

// ---------------- weight repack: fp32 row-major -> lane-tiled bf16 frags ----------------
__device__ __forceinline__ void dec(int i, int kslog, int& m, int& k) {
    int f = i >> 9, q = i & 511;
    int lane = q >> 3, j = q & 7;
    int lx = lane & 15, lq = lane >> 4;
    int mt = f >> kslog, ks = f & ((1 << kslog) - 1);
    m = mt * 16 + lx;
    k = ks * 32 + lq * 8 + j;
}

__global__ __launch_bounds__(256) void wprep_kernel(
    const float* __restrict__ fr1_w, const float* __restrict__ fr2_w, const float* __restrict__ fr3_w,
    const float* __restrict__ fo1_w, const float* __restrict__ fo2_w, const float* __restrict__ fo3_w,
    ushort* __restrict__ wsu)
{
    int idx = blockIdx.x * 256 + threadIdx.x;
    if (idx >= WSU_TOTAL) return;
    int m, k; float v;
    if (idx < 16384)       { dec(idx,          1, m, k); v = (k < PP) ? fr1_w[m * 96 + k] : 0.f; }
    else if (idx < 32768)  { dec(idx - 16384,  1, m, k); v = (k < PP) ? fr1_w[m * 96 + PP + k] : 0.f; }
    else if (idx < 65536)  { dec(idx - 32768,  3, m, k); v = fr2_w[m * 256 + k]; }
    else if (idx < 73728)  { dec(idx - 65536,  2, m, k); v = fr3_w[m * 128 + k]; }
    else if (idx < 106496) { dec(idx - 73728,  2, m, k); v = (k < 64) ? fo1_w[m * 112 + PP + k]
                                                           : (k < 112 ? fo1_w[m * 112 + (k - 64)] : 0.f); }
    else if (idx < 139264) { dec(idx - 106496, 3, m, k); v = fo2_w[m * 256 + k]; }
    else                   { dec(idx - 139264, 2, m, k); v = fo3_w[m * 128 + k]; }
    wsu[idx] = f2b(v);
}

// ---------------- mega kernel: one block per batch, 256 thr, 2 blocks/CU ----------------
__global__ __launch_bounds__(256) void meg_kernel(
    const float* __restrict__ x,
    const float* __restrict__ scl, const float* __restrict__ bia,
    const ushort* __restrict__ wsu,
    const float* __restrict__ fr1_b, const float* __restrict__ fr2_b, const float* __restrict__ fr3_b,
    const float* __restrict__ fo1_b, const float* __restrict__ fo2_b, const float* __restrict__ fo3_b,
    const float* __restrict__ fc1_w, const float* __restrict__ fc1_b,
    const float* __restrict__ fc2_w, const float* __restrict__ fc2_b,
    const float* __restrict__ fc3_w, const float* __restrict__ fc3_b,
    float* __restrict__ out)
{
    __shared__ __align__(16) ushort L[LDSE];

    int b = blockIdx.x, t = threadIdx.x;
    int w = t >> 6, l = t & 63, lx = l & 15, lq = l >> 4;

    // ---- xnT [64][64] into A2WO region (cols 48..63 zero)
    for (int i = t; i < 4096; i += 256) {
        int n = i >> 6, k = i & 63;
        float v = (k < PP) ? x[b * PP * NN + k * NN + n] * scl[k] + bia[k] : 0.f;
        L[A2WO + sidx(n, k, 64)] = f2b(v);
    }
    __syncthreads();

    // ---- GEMM R: S1R = fr1R.xn + b1   (wave w: m-tiles 4w..4w+3)
    {
        f32x4 a[4][4];
#pragma unroll
        for (int j = 0; j < 4; ++j)
#pragma unroll
            for (int nt = 0; nt < 4; ++nt) a[j][nt] = (f32x4){0.f,0.f,0.f,0.f};
#pragma unroll
        for (int ks = 0; ks < 2; ++ks) {
            bf16x8 Bf[4];
#pragma unroll
            for (int nt = 0; nt < 4; ++nt) Bf[nt] = ldfrag(L + A2WO, nt * 16 + lx, ks * 32 + lq * 8, 64);
#pragma unroll
            for (int j = 0; j < 4; ++j) {
                bf16x8 Af = gfrag(wsu + T1R, (4 * w + j) * 2 + ks, l);
#pragma unroll
                for (int nt = 0; nt < 4; ++nt) a[j][nt] = MFMA(Af, Bf[nt], a[j][nt]);
            }
        }
#pragma unroll
        for (int j = 0; j < 4; ++j) {
            int ch0 = (4 * w + j) * 16 + lq * 4;
            float4 bi = *(const float4*)(fr1_b + ch0);
#pragma unroll
            for (int nt = 0; nt < 4; ++nt) stRaw(L + S1RO, nt * 16 + lx, ch0, 256, a[j][nt], bi);
        }
    }
    // ---- GEMM S: S1S = fr1S.xn (no bias)
    {
        f32x4 a[4][4];
#pragma unroll
        for (int j = 0; j < 4; ++j)
#pragma unroll
            for (int nt = 0; nt < 4; ++nt) a[j][nt] = (f32x4){0.f,0.f,0.f,0.f};
#pragma unroll
        for (int ks = 0; ks < 2; ++ks) {
            bf16x8 Bf[4];
#pragma unroll
            for (int nt = 0; nt < 4; ++nt) Bf[nt] = ldfrag(L + A2WO, nt * 16 + lx, ks * 32 + lq * 8, 64);
#pragma unroll
            for (int j = 0; j < 4; ++j) {
                bf16x8 Af = gfrag(wsu + T1S, (4 * w + j) * 2 + ks, l);
#pragma unroll
                for (int nt = 0; nt < 4; ++nt) a[j][nt] = MFMA(Af, Bf[nt], a[j][nt]);
            }
        }
        float4 zb = make_float4(0.f, 0.f, 0.f, 0.f);
#pragma unroll
        for (int j = 0; j < 4; ++j) {
            int ch0 = (4 * w + j) * 16 + lq * 4;
#pragma unroll
            for (int nt = 0; nt < 4; ++nt) stRaw(L + S1SO, nt * 16 + lx, ch0, 256, a[j][nt], zb);
        }
    }
    __syncthreads();

    // ================= phase E: 16 receivers per wave, zero barriers =================
    ushort* a2w = L + A2WO + w * 2048;     // wave-private [16][128]
#pragma unroll 1
    for (int i = 0; i < 16; ++i) {
        int r = w * 16 + i;
        float part[4] = {0.f, 0.f, 0.f, 0.f};
#pragma unroll 1
        for (int p = 0; p < 2; ++p) {
            int eA = p * 32 + lx, eB = eA + 16;
            int sA = eA + (eA >= r);
            int sB = eB + (eB >= r); if (sB > 63) sB = 63;   // pad edge 63

            // packed act1 B-frags for both 16-edge groups, all ks
            U8 bA[8], bB[8];
#pragma unroll
            for (int ks = 0; ks < 8; ++ks) {
                U8 fs, fa, fb;
                fs.v = ldfrag(L + S1RO, r,  ks * 32 + lq * 8, 256);
                fa.v = ldfrag(L + S1SO, sA, ks * 32 + lq * 8, 256);
                fb.v = ldfrag(L + S1SO, sB, ks * 32 + lq * 8, 256);
#pragma unroll
                for (int jj = 0; jj < 4; ++jj) {
                    float r0 = loF(fs.u[jj]), r1 = hiF(fs.u[jj]);
                    bA[ks].u[jj] = pku(fmaxf(r0 + loF(fa.u[jj]), 0.f), fmaxf(r1 + hiF(fa.u[jj]), 0.f));
                    bB[ks].u[jj] = pku(fmaxf(r0 + loF(fb.u[jj]), 0.f), fmaxf(r1 + hiF(fb.u[jj]), 0.f));
                }
            }
            // L2: fr2 streamed from L2-cached workspace
            f32x4 acc2[8][2];
#pragma unroll
            for (int m = 0; m < 8; ++m) { acc2[m][0] = (f32x4){0.f,0.f,0.f,0.f}; acc2[m][1] = (f32x4){0.f,0.f,0.f,0.f}; }
#pragma unroll
            for (int m = 0; m < 8; ++m) {
                bf16x8 Af[8];
#pragma unroll
                for (int ks = 0; ks < 8; ++ks) Af[ks] = gfrag(wsu + T2O, m * 8 + ks, l);
#pragma unroll
                for (int ks = 0; ks < 8; ++ks) {
                    acc2[m][0] = MFMA(Af[ks], bA[ks].v, acc2[m][0]);
                    acc2[m][1] = MFMA(Af[ks], bB[ks].v, acc2[m][1]);
                }
            }
            // L3 per 16-edge group (transposed: edges = M), fr3 streamed
#pragma unroll 1
            for (int cc = 0; cc < 2; ++cc) {
#pragma unroll
                for (int m = 0; m < 8; ++m) {
                    float4 b2 = *(const float4*)(fr2_b + m * 16 + lq * 4);
                    stAct(a2w, lx, m * 16 + lq * 4, 128, acc2[m][cc], b2);
                }
                f32x4 acc3[4];
#pragma unroll
                for (int n3 = 0; n3 < 4; ++n3) acc3[n3] = (f32x4){0.f,0.f,0.f,0.f};
#pragma unroll
                for (int ks3 = 0; ks3 < 4; ++ks3) {
                    bf16x8 af = ldfrag(a2w, lx, ks3 * 32 + lq * 8, 128);
#pragma unroll
                    for (int n3 = 0; n3 < 4; ++n3) {
                        bf16x8 Bw = gfrag(wsu + T3O, n3 * 4 + ks3, l);
                        acc3[n3] = MFMA(af, Bw, acc3[n3]);
                    }
                }
                bool mpad = (p == 1) && (cc == 1) && (lq == 3);
#pragma unroll
                for (int n3 = 0; n3 < 4; ++n3) {
                    float bv = fr3_b[n3 * 16 + lx];
                    float s = fmaxf(acc3[n3][0] + bv, 0.f) + fmaxf(acc3[n3][1] + bv, 0.f)
                            + fmaxf(acc3[n3][2] + bv, 0.f);
                    float s3 = fmaxf(acc3[n3][3] + bv, 0.f);
                    part[n3] += s + (mpad ? 0.f : s3);
                }
            }
        }
#pragma unroll
        for (int n3 = 0; n3 < 4; ++n3) {
            part[n3] += __shfl_xor(part[n3], 16, 64);
            part[n3] += __shfl_xor(part[n3], 32, 64);
        }
        if (lq == 0) {
#pragma unroll
            for (int n3 = 0; n3 < 4; ++n3)
                L[S1RO + sidx(r, n3 * 16 + lx, 256)] = f2b(part[n3]);
        }
    }
    __syncthreads();

    // ================= phase N =================
    // xn into S1R cols 64..111 (act0 = [ebar 0..63 | xn 64..111 | stale-x-zero-weight])
    for (int i = t; i < 4096; i += 256) {
        int n = i >> 6, k = i & 63;
        if (k < PP) {
            float v = x[b * PP * NN + k * NN + n] * scl[k] + bia[k];
            L[S1RO + sidx(n, 64 + k, 256)] = f2b(v);
        }
    }
    __syncthreads();

    // L1N: M=256 (wave: 4 mt), N=64 nodes, K=128; fo1 streamed
    {
        f32x4 aN[4][4];
#pragma unroll
        for (int j = 0; j < 4; ++j)
#pragma unroll
            for (int nt = 0; nt < 4; ++nt) aN[j][nt] = (f32x4){0.f,0.f,0.f,0.f};
#pragma unroll
        for (int ks = 0; ks < 4; ++ks) {
            bf16x8 Bf[4];
#pragma unroll
            for (int nt = 0; nt < 4; ++nt) Bf[nt] = ldfrag(L + S1RO, nt * 16 + lx, ks * 32 + lq * 8, 256);
#pragma unroll
            for (int j = 0; j < 4; ++j) {
                bf16x8 Af = gfrag(wsu + TO1, (4 * w + j) * 4 + ks, l);
#pragma unroll
                for (int nt = 0; nt < 4; ++nt) aN[j][nt] = MFMA(Af, Bf[nt], aN[j][nt]);
            }
        }
#pragma unroll
        for (int j = 0; j < 4; ++j) {
            int ch0 = (4 * w + j) * 16 + lq * 4;
            float4 bi = *(const float4*)(fo1_b + ch0);
#pragma unroll
            for (int nt = 0; nt < 4; ++nt) stAct(L + S1SO, nt * 16 + lx, ch0, 256, aN[j][nt], bi);
        }
    }
    __syncthreads();

    // L2N: M=128 (wave: 2 mt), N=64, K=256; fo2 streamed -> act2N @ A2WO [64][128]
    {
        f32x4 a2N[2][4];
#pragma unroll
        for (int j = 0; j < 2; ++j)
#pragma unroll
            for (int nt = 0; nt < 4; ++nt) a2N[j][nt] = (f32x4){0.f,0.f,0.f,0.f};
#pragma unroll
        for (int ks = 0; ks < 8; ++ks) {
            bf16x8 Bf[4];
#pragma unroll
            for (int nt = 0; nt < 4; ++nt) Bf[nt] = ldfrag(L + S1SO, nt * 16 + lx, ks * 32 + lq * 8, 256);
#pragma unroll
            for (int j = 0; j < 2; ++j) {
                bf16x8 Af = gfrag(wsu + TO2, (2 * w + j) * 8 + ks, l);
#pragma unroll
                for (int nt = 0; nt < 4; ++nt) a2N[j][nt] = MFMA(Af, Bf[nt], a2N[j][nt]);
            }
        }
        __syncthreads();   // A2WO (phase-E scratch) fully dead across all waves
#pragma unroll
        for (int j = 0; j < 2; ++j) {
            int ch0 = (2 * w + j) * 16 + lq * 4;
            float4 bi = *(const float4*)(fo2_b + ch0);
#pragma unroll
            for (int nt = 0; nt < 4; ++nt) stAct(L + A2WO, nt * 16 + lx, ch0, 128, a2N[j][nt], bi);
        }
    }
    __syncthreads();

    // L3N: M=64 (wave: mt w), N=64 nodes, K=128; fo3 streamed; relu+bias, sum over nodes
    {
        f32x4 a3N[4];
#pragma unroll
        for (int nt = 0; nt < 4; ++nt) a3N[nt] = (f32x4){0.f,0.f,0.f,0.f};
#pragma unroll
        for (int ks3 = 0; ks3 < 4; ++ks3) {
            bf16x8 Af = gfrag(wsu + TO3, w * 4 + ks3, l);
#pragma unroll
            for (int nt = 0; nt < 4; ++nt) {
                bf16x8 Bf = ldfrag(L + A2WO, nt * 16 + lx, ks3 * 32 + lq * 8, 128);
                a3N[nt] = MFMA(Af, Bf, a3N[nt]);
            }
        }
        float4 b3 = *(const float4*)(fo3_b + 16 * w + lq * 4);
        float o0 = 0.f, o1 = 0.f, o2 = 0.f, o3 = 0.f;
#pragma unroll
        for (int nt = 0; nt < 4; ++nt) {
            o0 += fmaxf(a3N[nt][0] + b3.x, 0.f);
            o1 += fmaxf(a3N[nt][1] + b3.y, 0.f);
            o2 += fmaxf(a3N[nt][2] + b3.z, 0.f);
            o3 += fmaxf(a3N[nt][3] + b3.w, 0.f);
        }
#pragma unroll
        for (int off = 8; off >= 1; off >>= 1) {
            o0 += __shfl_xor(o0, off, 16);
            o1 += __shfl_xor(o1, off, 16);
            o2 += __shfl_xor(o2, off, 16);
            o3 += __shfl_xor(o3, off, 16);
        }
        if (lx == 0) {
            float* red = (float*)(L + S1SO);
            *(float4*)&red[16 * w + lq * 4] = make_float4(o0, o1, o2, o3);
        }
    }
    __syncthreads();

    // ---- final FCs (fp32)
    {
        float* red = (float*)(L + S1SO);
        float* h1  = red + 64;
        float* h2  = red + 96;
        if (t < 25) {
            float s = fc1_b[t];
            for (int k = 0; k < 64; ++k) s += fc1_w[t * 64 + k] * red[k];
            h1[t] = s;
        }
        __syncthreads();
        if (t < 15) {
            float s = fc2_b[t];
            for (int k = 0; k < 25; ++k) s += fc2_w[t * 25 + k] * h1[k];
            h2[t] = s;
        }
        __syncthreads();
        if (t < 5) {
            float s = fc3_b[t];
            for (int k = 0; k < 15; ++k) s += fc3_w[t * 15 + k] * h2[k];
            out[b * 5 + t] = s;
        }
    }
}

extern "C" void kernel_launch(void* const* d_in, const int* in_sizes, int n_in,
                              void* d_out, int out_size, void* d_ws, size_t ws_size,
                              hipStream_t stream)
{
    const float* x        = (const float*)d_in[0];
    const float* bn_gamma = (const float*)d_in[3];
    const float* bn_beta  = (const float*)d_in[4];
    const float* fr1_w = (const float*)d_in[5];
    const float* fr1_b = (const float*)d_in[6];
    const float* fr2_w = (const float*)d_in[7];
    const float* fr2_b = (const float*)d_in[8];
    const float* fr3_w = (const float*)d_in[9];
    const float* fr3_b = (const float*)d_in[10];
    const float* fo1_w = (const float*)d_in[11];
    const float* fo1_b = (const float*)d_in[12];
    const float* fo2_w = (const float*)d_in[13];
    const float* fo2_b = (const float*)d_in[14];
    const float* fo3_w = (const float*)d_in[15];
    const float* fo3_b = (const float*)d_in[16];
    const float* fc1_w = (const float*)d_in[17];
    const float* fc1_b = (const float*)d_in[18];
    const float* fc2_w = (const float*)d_in[19];
    const float* fc2_b = (const float*)d_in[20];
    const float* fc3_w = (const float*)d_in[21];
    const float* fc3_b = (const float*)d_in[22];

    float*  ws    = (float*)d_ws;
    float*  scale = ws;            // 64 floats
    float*  bias  = ws + 64;       // 64 floats
    ushort* wsu   = (ushort*)(ws + 128);
    float*  out   = (float*)d_out;

    bn_stats_kernel<<<dim3(PP), dim3(256), 0, stream>>>(x, bn_gamma, bn_beta, scale, bias);
    wprep_kernel<<<dim3((WSU_TOTAL + 255) / 256), dim3(256), 0, stream>>>(
        fr1_w, fr2_w, fr3_w, fo1_w, fo2_w, fo3_w, wsu);
    meg_kernel<<<dim3(BB), dim3(256), 0, stream>>>(
        x, scale, bias, wsu,
        fr1_b, fr2_b, fr3_b, fo1_b, fo2_b, fo3_b,
        fc1_w, fc1_b, fc2_w, fc2_b, fc3_w, fc3_b, out);
}

// Round 8
// 313.239 us; speedup vs baseline: 1.3045x; 1.3045x over previous
//
#include <hip/hip_runtime.h>
#include <hip/hip_bf16.h>

#define BB 256
#define PP 48
#define NN 64
#define EPSBN 1e-5f

typedef __attribute__((ext_vector_type(8))) short bf16x8;
typedef __attribute__((ext_vector_type(4))) float f32x4;

// ---- LDS regions (ushort offsets), total 81920 ushorts = 163840 B (160 KiB) ----
#define BIGO 0       // 32768: fr1R/[+16384]fr1S -> fr2 [128][256]   | N: fo1 [256][128] -> fo2 [128][256]
#define S1SO 32768   // 16384: S1S [64][256]                          | N: act1N [64][256]
#define S1RO 49152   // 16384: S1R [64][256]; cols 0..63 -> ebar      | N: fo3 [64][128]
#define A2WO 65536   // 16384: phase E: 8 waves x 2048 private act2   | N: act2N [64][128]
#define XNT2 73728   //  4096: xnT [64][64] (clobbered by waves 4..7 a2w in phase E; restaged)
#define REDO 77824   //  4096: phase N red/h1/h2 (floats)
#define LDSE 81920

// fr3 lane-tiled frags in workspace: 16 frags x 512 ushorts
#define WSU3_TOTAL 8192

union U8 { bf16x8 v; unsigned u[4]; };

__device__ __forceinline__ unsigned pku(float a, float b) {
    union { __hip_bfloat162 h; unsigned u; } cv;
    cv.h = __float22bfloat162_rn(make_float2(a, b));
    return cv.u;
}
__device__ __forceinline__ ushort f2b(float f) {
    union { float f; unsigned u; } a; a.f = f;
    unsigned u = a.u + 0x7FFFu + ((a.u >> 16) & 1u);
    return (ushort)(u >> 16);
}
__device__ __forceinline__ float loF(unsigned u) { union { unsigned x; float f; } c; c.x = u << 16; return c.f; }
__device__ __forceinline__ float hiF(unsigned u) { union { unsigned x; float f; } c; c.x = u & 0xffff0000u; return c.f; }

__device__ __forceinline__ int sidx(int row, int k, int kpad) {
    return row * kpad + ((((k >> 3) ^ (row & 7)) << 3) | (k & 7));
}
__device__ __forceinline__ bf16x8 ldfrag(const ushort* buf, int row, int k, int kpad) {
    return *(const bf16x8*)(buf + row * kpad + (((k >> 3) ^ (row & 7)) << 3));
}
// coalesced tiled-fragment load from global workspace: frag f, lane l -> 16 B
__device__ __forceinline__ bf16x8 gfrag(const ushort* base, int f, int l) {
    return *(const bf16x8*)(base + ((f << 6) + l) * 8);
}
__device__ __forceinline__ f32x4 MFMA(bf16x8 a, bf16x8 b, f32x4 c) {
    return __builtin_amdgcn_mfma_f32_16x16x32_bf16(a, b, c, 0, 0, 0);
}
__device__ __forceinline__ void stAct(ushort* buf, int row, int c0, int kpad, f32x4 a, float4 bi) {
    uint2 o;
    o.x = pku(fmaxf(a[0] + bi.x, 0.f), fmaxf(a[1] + bi.y, 0.f));
    o.y = pku(fmaxf(a[2] + bi.z, 0.f), fmaxf(a[3] + bi.w, 0.f));
    *(uint2*)(buf + row * kpad + ((((c0 >> 3) ^ (row & 7)) << 3) | (c0 & 7))) = o;
}
__device__ __forceinline__ void stRaw(ushort* buf, int row, int c0, int kpad, f32x4 a, float4 bi) {
    uint2 o;
    o.x = pku(a[0] + bi.x, a[1] + bi.y);
    o.y = pku(a[2] + bi.z, a[3] + bi.w);
    *(uint2*)(buf + row * kpad + ((((c0 >> 3) ^ (row & 7)) << 3) | (c0 & 7))) = o;
}

// ---------------- batchnorm stats ----------------
__global__ __launch_bounds__(256) void bn_stats_kernel(
    const float* __restrict__ x, const float* __restrict__ gamma,
    const float* __restrict__ beta, float* __restrict__ scale, float* __restrict__ bias)
{
    __shared__ float s_sum[256], s_sq[256];
    int p = blockIdx.x, t = threadIdx.x;
    float sum = 0.f, sq = 0.f;
    for (int i = t; i < BB * NN; i += 256) {
        int b = i >> 6, n = i & 63;
        float v = x[b * PP * NN + p * NN + n];
        sum += v; sq += v * v;
    }
    s_sum[t] = sum; s_sq[t] = sq;
    __syncthreads();
    for (int off = 128; off > 0; off >>= 1) {
        if (t < off) { s_sum[t] += s_sum[t + off]; s_sq[t] += s_sq[t + off]; }
        __syncthreads();
    }
    if (t == 0) {
        float inv = 1.f / (float)(BB * NN);
        float mean = s_sum[0] * inv;
        float var  = s_sq[0] * inv - mean * mean;
        float sc   = gamma[p] * rsqrtf(var + EPSBN);
        scale[p] = sc;
        bias[p]  = beta[p] - mean * sc;
    }
}

// ---------------- fr3 repack: row-major fp32 -> lane-tiled bf16 frags ----------------
__global__ __launch_bounds__(256) void wprep3_kernel(
    const float* __restrict__ fr3_w, ushort* __restrict__ wsu3)
{
    int idx = blockIdx.x * 256 + threadIdx.x;
    if (idx >= WSU3_TOTAL) return;
    int f = idx >> 9, q = idx & 511;
    int lane = q >> 3, j = q & 7;
    int lx = lane & 15, lq = lane >> 4;
    int mt = f >> 2, ks = f & 3;
    int m = mt * 16 + lx;
    int k = ks * 32 + lq * 8 + j;
    wsu3[idx] = f2b(fr3_w[m * 128 + k]);
}

// ---------------- mega kernel: one block per batch, 8 waves, 2 waves/SIMD ----------------
__global__ __launch_bounds__(512, 1) void meg_kernel(
    const float* __restrict__ x,
    const float* __restrict__ scl, const float* __restrict__ bia,
    const ushort* __restrict__ wsu3,
    const float* __restrict__ fr1_w, const float* __restrict__ fr1_b,
    const float* __restrict__ fr2_w, const float* __restrict__ fr2_b,
    const float* __restrict__ fr3_b,
    const float* __restrict__ fo1_w, const float* __restrict__ fo1_b,
    const float* __restrict__ fo2_w, const float* __restrict__ fo2_b,
    const float* __restrict__ fo3_w, const float* __restrict__ fo3_b,
    const float* __restrict__ fc1_w, const float* __restrict__ fc1_b,
    const float* __restrict__ fc2_w, const float* __restrict__ fc2_b,
    const float* __restrict__ fc3_w, const float* __restrict__ fc3_b,
    float* __restrict__ out)
{
    __shared__ __align__(16) ushort L[LDSE];

    int b = blockIdx.x, t = threadIdx.x;
    int w = t >> 6, l = t & 63, lx = l & 15, lq = l >> 4;

    // ---- xnT [64][64] (cols 48..63 zero)
    for (int i = t; i < 4096; i += 512) {
        int n = i >> 6, k = i & 63;
        float v = (k < PP) ? x[b * PP * NN + k * NN + n] * scl[k] + bia[k] : 0.f;
        L[XNT2 + sidx(n, k, 64)] = f2b(v);
    }
    // ---- fr1 receiver / sender halves into BIG
    for (int i = t; i < 16384; i += 512) {
        int ch = i >> 6, k = i & 63;
        L[BIGO + sidx(ch, k, 64)]         = f2b((k < PP) ? fr1_w[ch * 96 + k] : 0.f);
        L[BIGO + 16384 + sidx(ch, k, 64)] = f2b((k < PP) ? fr1_w[ch * 96 + PP + k] : 0.f);
    }
    __syncthreads();

    // ---- GEMM1+2 fused: S1R = fr1R.xn + b1, S1S = fr1S.xn  (each wave: 2 m-tiles)
    {
        f32x4 aR[2][4], aS[2][4];
#pragma unroll
        for (int j = 0; j < 2; ++j)
#pragma unroll
            for (int nt = 0; nt < 4; ++nt) { aR[j][nt] = (f32x4){0.f,0.f,0.f,0.f}; aS[j][nt] = (f32x4){0.f,0.f,0.f,0.f}; }
#pragma unroll
        for (int ks = 0; ks < 2; ++ks) {
            bf16x8 Bf[4];
#pragma unroll
            for (int nt = 0; nt < 4; ++nt) Bf[nt] = ldfrag(L + XNT2, nt * 16 + lx, ks * 32 + lq * 8, 64);
#pragma unroll
            for (int j = 0; j < 2; ++j) {
                bf16x8 AfR = ldfrag(L + BIGO,         (2 * w + j) * 16 + lx, ks * 32 + lq * 8, 64);
                bf16x8 AfS = ldfrag(L + BIGO + 16384, (2 * w + j) * 16 + lx, ks * 32 + lq * 8, 64);
#pragma unroll
                for (int nt = 0; nt < 4; ++nt) {
                    aR[j][nt] = MFMA(AfR, Bf[nt], aR[j][nt]);
                    aS[j][nt] = MFMA(AfS, Bf[nt], aS[j][nt]);
                }
            }
        }
        __syncthreads();   // BIG reads done; restage fr2 below
#pragma unroll
        for (int j = 0; j < 2; ++j) {
            int ch0 = (2 * w + j) * 16 + lq * 4;
            float4 bi = *(const float4*)(fr1_b + ch0);
            float4 zb = make_float4(0.f, 0.f, 0.f, 0.f);
#pragma unroll
            for (int nt = 0; nt < 4; ++nt) {
                stRaw(L + S1RO, nt * 16 + lx, ch0, 256, aR[j][nt], bi);
                stRaw(L + S1SO, nt * 16 + lx, ch0, 256, aS[j][nt], zb);
            }
        }
    }
    // ---- fr2 [128][256] -> BIG
    for (int i = t; i < 16384; i += 512) {
        int ch = i >> 7, k2 = (i & 127) * 2;
        float2 v = *(const float2*)(fr2_w + ch * 256 + k2);
        *(unsigned*)(L + BIGO + sidx(ch, k2, 256)) = pku(v.x, v.y);
    }
    // ---- hoist small biases only (36 regs)
    float4 b2c[8];
#pragma unroll
    for (int m = 0; m < 8; ++m) b2c[m] = *(const float4*)(fr2_b + m * 16 + lq * 4);
    float b3c[4];
#pragma unroll
    for (int n3 = 0; n3 < 4; ++n3) b3c[n3] = fr3_b[n3 * 16 + lx];
    __syncthreads();

    // ================= phase E: 8 receivers per wave, zero barriers =================
    ushort* a2w = L + A2WO + w * 2048;     // wave-private [16][128]
#pragma unroll 1
    for (int i = 0; i < 8; ++i) {
        int r = w * 8 + i;
        // receiver's L1 pre-act, kept PACKED (32 VGPRs)
        U8 s1rp[8];
#pragma unroll
        for (int ks = 0; ks < 8; ++ks) s1rp[ks].v = ldfrag(L + S1RO, r, ks * 32 + lq * 8, 256);

        float part[4] = {0.f, 0.f, 0.f, 0.f};
#pragma unroll 1
        for (int p = 0; p < 2; ++p) {
            int eA = p * 32 + lx, eB = eA + 16;
            int sA = eA + (eA >= r);
            int sB = eB + (eB >= r); if (sB > 63) sB = 63;   // pad edge 63

            f32x4 acc2[8][2];
#pragma unroll
            for (int m = 0; m < 8; ++m) { acc2[m][0] = (f32x4){0.f,0.f,0.f,0.f}; acc2[m][1] = (f32x4){0.f,0.f,0.f,0.f}; }
#pragma unroll
            for (int ks = 0; ks < 8; ++ks) {
                U8 fa, fb;
                fa.v = ldfrag(L + S1SO, sA, ks * 32 + lq * 8, 256);
                fb.v = ldfrag(L + S1SO, sB, ks * 32 + lq * 8, 256);
                U8 bA, bB;
#pragma unroll
                for (int jj = 0; jj < 4; ++jj) {
                    float r0 = loF(s1rp[ks].u[jj]);
                    float r1 = hiF(s1rp[ks].u[jj]);
                    bA.u[jj] = pku(fmaxf(r0 + loF(fa.u[jj]), 0.f), fmaxf(r1 + hiF(fa.u[jj]), 0.f));
                    bB.u[jj] = pku(fmaxf(r0 + loF(fb.u[jj]), 0.f), fmaxf(r1 + hiF(fb.u[jj]), 0.f));
                }
#pragma unroll
                for (int m = 0; m < 8; ++m) {
                    bf16x8 Af = ldfrag(L + BIGO, m * 16 + lx, ks * 32 + lq * 8, 256);
                    acc2[m][0] = MFMA(Af, bA.v, acc2[m][0]);
                    acc2[m][1] = MFMA(Af, bB.v, acc2[m][1]);
                }
            }
#pragma unroll
            for (int cc = 0; cc < 2; ++cc) {
#pragma unroll
                for (int m = 0; m < 8; ++m)
                    stAct(a2w, lx, m * 16 + lq * 4, 128, acc2[m][cc], b2c[m]);
                f32x4 acc3[4];
#pragma unroll
                for (int n3 = 0; n3 < 4; ++n3) acc3[n3] = (f32x4){0.f,0.f,0.f,0.f};
#pragma unroll
                for (int ks3 = 0; ks3 < 4; ++ks3) {
                    bf16x8 af = ldfrag(a2w, lx, ks3 * 32 + lq * 8, 128);
#pragma unroll
                    for (int n3 = 0; n3 < 4; ++n3) {
                        bf16x8 Bw = gfrag(wsu3, n3 * 4 + ks3, l);   // fr3, L2-hot
                        acc3[n3] = MFMA(af, Bw, acc3[n3]);
                    }
                }
                bool mpad = (p == 1) && (cc == 1) && (lq == 3);
#pragma unroll
                for (int n3 = 0; n3 < 4; ++n3) {
                    float bv = b3c[n3];
                    float s = fmaxf(acc3[n3][0] + bv, 0.f) + fmaxf(acc3[n3][1] + bv, 0.f)
                            + fmaxf(acc3[n3][2] + bv, 0.f);
                    float s3 = fmaxf(acc3[n3][3] + bv, 0.f);
                    part[n3] += s + (mpad ? 0.f : s3);
                }
            }
        }
#pragma unroll
        for (int n3 = 0; n3 < 4; ++n3) {
            part[n3] += __shfl_xor(part[n3], 16, 64);
            part[n3] += __shfl_xor(part[n3], 32, 64);
        }
        if (lq == 0) {
#pragma unroll
            for (int n3 = 0; n3 < 4; ++n3)
                L[S1RO + sidx(r, n3 * 16 + lx, 256)] = f2b(part[n3]);
        }
    }
    __syncthreads();

    // ================= phase N =================
    // fo1 -> BIG [256][128] (cols 0..63 ebar part, 64..111 xn part)
    for (int i = t; i < 32768; i += 512) {
        int ch = i >> 7, k = i & 127;
        float v = 0.f;
        if (k < 64)       v = fo1_w[ch * 112 + PP + k];
        else if (k < 112) v = fo1_w[ch * 112 + (k - 64)];
        L[BIGO + sidx(ch, k, 128)] = f2b(v);
    }
    // restage xnT (clobbered by waves 4..7 a2w in phase E)
    for (int i = t; i < 4096; i += 512) {
        int n = i >> 6, k = i & 63;
        float v = (k < PP) ? x[b * PP * NN + k * NN + n] * scl[k] + bia[k] : 0.f;
        L[XNT2 + sidx(n, k, 64)] = f2b(v);
    }
    __syncthreads();

    // L1N: M=256 (wave: 2 m-tiles), N=64 nodes, K=128 (ks 0,1 ebar from S1RO; ks 2,3 from XNT2)
    {
        f32x4 accN[2][4];
#pragma unroll
        for (int j = 0; j < 2; ++j)
#pragma unroll
            for (int nt = 0; nt < 4; ++nt) accN[j][nt] = (f32x4){0.f,0.f,0.f,0.f};
#pragma unroll
        for (int ks = 0; ks < 4; ++ks) {
            bf16x8 Bf[4];
#pragma unroll
            for (int nt = 0; nt < 4; ++nt)
                Bf[nt] = (ks < 2) ? ldfrag(L + S1RO, nt * 16 + lx, ks * 32 + lq * 8, 256)
                                  : ldfrag(L + XNT2, nt * 16 + lx, (ks - 2) * 32 + lq * 8, 64);
#pragma unroll
            for (int j = 0; j < 2; ++j) {
                bf16x8 Af = ldfrag(L + BIGO, (2 * w + j) * 16 + lx, ks * 32 + lq * 8, 128);
#pragma unroll
                for (int nt = 0; nt < 4; ++nt) accN[j][nt] = MFMA(Af, Bf[nt], accN[j][nt]);
            }
        }
        __syncthreads();   // BIG/S1RO/XNT2 reads done
#pragma unroll
        for (int j = 0; j < 2; ++j) {
            int ch0 = (2 * w + j) * 16 + lq * 4;
            float4 bi = *(const float4*)(fo1_b + ch0);
#pragma unroll
            for (int nt = 0; nt < 4; ++nt)
                stAct(L + S1SO, nt * 16 + lx, ch0, 256, accN[j][nt], bi);
        }
    }
    // fo2 -> BIG [128][256]; fo3 -> S1RO [64][128]
    for (int i = t; i < 16384; i += 512) {
        int ch = i >> 7, k2 = (i & 127) * 2;
        float2 v = *(const float2*)(fo2_w + ch * 256 + k2);
        *(unsigned*)(L + BIGO + sidx(ch, k2, 256)) = pku(v.x, v.y);
    }
    for (int i = t; i < 4096; i += 512) {
        int ch = i >> 6, k2 = (i & 63) * 2;
        float2 v = *(const float2*)(fo3_w + ch * 128 + k2);
        *(unsigned*)(L + S1RO + sidx(ch, k2, 128)) = pku(v.x, v.y);
    }
    __syncthreads();

    // L2N: M=128 (wave: m-tile w), N=64, K=256 -> act2N @ A2WO [64][128]
    {
        f32x4 a2N[4];
#pragma unroll
        for (int nt = 0; nt < 4; ++nt) a2N[nt] = (f32x4){0.f,0.f,0.f,0.f};
#pragma unroll
        for (int ks = 0; ks < 8; ++ks) {
            bf16x8 Bf[4];
#pragma unroll
            for (int nt = 0; nt < 4; ++nt) Bf[nt] = ldfrag(L + S1SO, nt * 16 + lx, ks * 32 + lq * 8, 256);
            bf16x8 Af = ldfrag(L + BIGO, w * 16 + lx, ks * 32 + lq * 8, 256);
#pragma unroll
            for (int nt = 0; nt < 4; ++nt) a2N[nt] = MFMA(Af, Bf[nt], a2N[nt]);
        }
        int ch0 = w * 16 + lq * 4;
        float4 bi = *(const float4*)(fo2_b + ch0);
#pragma unroll
        for (int nt = 0; nt < 4; ++nt)
            stAct(L + A2WO, nt * 16 + lx, ch0, 128, a2N[nt], bi);
    }
    __syncthreads();

    // L3N: M=64 (fo3 ch), N=64 nodes, K=128 (waves 0..3); relu+bias, sum over nodes
    if (w < 4) {
        f32x4 a3N[4];
#pragma unroll
        for (int nt = 0; nt < 4; ++nt) a3N[nt] = (f32x4){0.f,0.f,0.f,0.f};
#pragma unroll
        for (int ks3 = 0; ks3 < 4; ++ks3) {
            bf16x8 Af = ldfrag(L + S1RO, 16 * w + lx, ks3 * 32 + lq * 8, 128);
#pragma unroll
            for (int nt = 0; nt < 4; ++nt) {
                bf16x8 Bf = ldfrag(L + A2WO, nt * 16 + lx, ks3 * 32 + lq * 8, 128);
                a3N[nt] = MFMA(Af, Bf, a3N[nt]);
            }
        }
        float4 b3 = *(const float4*)(fo3_b + 16 * w + lq * 4);
        float o0 = 0.f, o1 = 0.f, o2 = 0.f, o3 = 0.f;
#pragma unroll
        for (int nt = 0; nt < 4; ++nt) {
            o0 += fmaxf(a3N[nt][0] + b3.x, 0.f);
            o1 += fmaxf(a3N[nt][1] + b3.y, 0.f);
            o2 += fmaxf(a3N[nt][2] + b3.z, 0.f);
            o3 += fmaxf(a3N[nt][3] + b3.w, 0.f);
        }
#pragma unroll
        for (int off = 8; off >= 1; off >>= 1) {
            o0 += __shfl_xor(o0, off, 16);
            o1 += __shfl_xor(o1, off, 16);
            o2 += __shfl_xor(o2, off, 16);
            o3 += __shfl_xor(o3, off, 16);
        }
        if (lx == 0) {
            float* red = (float*)(L + REDO);
            *(float4*)&red[16 * w + lq * 4] = make_float4(o0, o1, o2, o3);
        }
    }
    __syncthreads();

    // ---- final FCs (fp32)
    {
        float* red = (float*)(L + REDO);
        float* h1  = red + 64;
        float* h2  = red + 96;
        if (t < 25) {
            float s = fc1_b[t];
            for (int k = 0; k < 64; ++k) s += fc1_w[t * 64 + k] * red[k];
            h1[t] = s;
        }
        __syncthreads();
        if (t < 15) {
            float s = fc2_b[t];
            for (int k = 0; k < 25; ++k) s += fc2_w[t * 25 + k] * h1[k];
            h2[t] = s;
        }
        __syncthreads();
        if (t < 5) {
            float s = fc3_b[t];
            for (int k = 0; k < 15; ++k) s += fc3_w[t * 15 + k] * h2[k];
            out[b * 5 + t] = s;
        }
    }
}

extern "C" void kernel_launch(void* const* d_in, const int* in_sizes, int n_in,
                              void* d_out, int out_size, void* d_ws, size_t ws_size,
                              hipStream_t stream)
{
    const float* x        = (const float*)d_in[0];
    const float* bn_gamma = (const float*)d_in[3];
    const float* bn_beta  = (const float*)d_in[4];
    const float* fr1_w = (const float*)d_in[5];
    const float* fr1_b = (const float*)d_in[6];
    const float* fr2_w = (const float*)d_in[7];
    const float* fr2_b = (const float*)d_in[8];
    const float* fr3_w = (const float*)d_in[9];
    const float* fr3_b = (const float*)d_in[10];
    const float* fo1_w = (const float*)d_in[11];
    const float* fo1_b = (const float*)d_in[12];
    const float* fo2_w = (const float*)d_in[13];
    const float* fo2_b = (const float*)d_in[14];
    const float* fo3_w = (const float*)d_in[15];
    const float* fo3_b = (const float*)d_in[16];
    const float* fc1_w = (const float*)d_in[17];
    const float* fc1_b = (const float*)d_in[18];
    const float* fc2_w = (const float*)d_in[19];
    const float* fc2_b = (const float*)d_in[20];
    const float* fc3_w = (const float*)d_in[21];
    const float* fc3_b = (const float*)d_in[22];

    float*  ws    = (float*)d_ws;
    float*  scale = ws;            // 64 floats
    float*  bias  = ws + 64;       // 64 floats
    ushort* wsu3  = (ushort*)(ws + 128);
    float*  out   = (float*)d_out;

    bn_stats_kernel<<<dim3(PP), dim3(256), 0, stream>>>(x, bn_gamma, bn_beta, scale, bias);
    wprep3_kernel<<<dim3(WSU3_TOTAL / 256), dim3(256), 0, stream>>>(fr3_w, wsu3);
    meg_kernel<<<dim3(BB), dim3(512), 0, stream>>>(
        x, scale, bias, wsu3,
        fr1_w, fr1_b, fr2_w, fr2_b, fr3_b,
        fo1_w, fo1_b, fo2_w, fo2_b, fo3_w, fo3_b,
        fc1_w, fc1_b, fc2_w, fc2_b, fc3_w, fc3_b, out);
}